// Round 1
// baseline (171.211 us; speedup 1.0000x reference)
//
#include <hip/hip_runtime.h>
#include <math.h>

#define B_ 4
#define D_ 32
#define H_ 192
#define W_ 192
#define HW_ (H_ * W_)

#define NT 5            // Taylor terms p = 1..5

#define TW 48           // 12 col-groups x 4 cols (b128)
#define TH 12
#define NTHR 256
#define ZCHUNK 16
#define NP (ZCHUNK + 8) // 24 staged planes; NP+1 = 25 pipelined iterations

#define XT_H 26         // TH + 14
#define XT_COLS 62      // TW + 14
#define XT_W 72         // %4==0 (b128-aligned rows)
#define XT_CELLS (XT_H * XT_COLS)   // 1612
#define NSEC 7
#define XT_SZ (XT_H * XT_W)         // 1872

// Stage-1 (h-conv) output buffer: per Taylor term, 12 rows x 64 cols (62 used)
#define R2_H 12
#define R2_S 68          // stride %32==4 -> rows de-staggered by one bank-quad
#define R2_PL (R2_H * R2_S)   // 816
#define RBUF (NT * R2_PL)     // 4080

#define SMEM_WORDS (2 * XT_SZ + 2 * RBUF)   // 3744 + 8160 = 11904 (47.6 KB)

#define NTAPS (B_ * 9 * 15 * 15)

__device__ inline float4 f4fma(float c, float4 a, float4 d) {
    d.x = fmaf(c, a.x, d.x); d.y = fmaf(c, a.y, d.y);
    d.z = fmaf(c, a.z, d.z); d.w = fmaf(c, a.w, d.w);
    return d;
}
__device__ inline float4 f4add(float4 a, float4 b) {
    a.x += b.x; a.y += b.y; a.z += b.z; a.w += b.w; return a;
}
__device__ inline float rfl(float x) {
    return __int_as_float(__builtin_amdgcn_readfirstlane(__float_as_int(x)));
}

// Separable-Taylor blur, stage order SWAPPED vs previous version:
//   stage 1: h-conv directly from staged plane xt (15 LDS reads shared
//            across all NT terms, 12x64 items) -> R'[n] (12 x 62)
//   stage 2: w-conv per term from R'[n] (5 reads/term) + z-scatter into acc
// Single barrier per plane; xt and R' double-buffered (pipelined p / p-1).
__global__ __launch_bounds__(NTHR)
void conv_kernel(const float* __restrict__ x,
                 const float* __restrict__ bet_xy,
                 const float* __restrict__ bet_z,
                 const float* __restrict__ alpha,
                 float* __restrict__ out) {
    __shared__ __align__(16) float smem[SMEM_WORDS];
    float* xtb = smem;                 // [2][XT_SZ]
    float* Rb  = smem + 2 * XT_SZ;     // [2][NT][R2_PL]
    float* red = smem;                 // alias: pre-loop only
    float* ct  = smem + 512;           // alias: pre-loop only, [NT][16]

    const int t  = threadIdx.x;
    const int w0 = blockIdx.x * TW;
    const int h0 = blockIdx.y * TH;
    const int bz = blockIdx.z;
    const int b  = bz & 3;
    const int z0 = (bz >> 2) * ZCHUNK;
    const float INV = 0.3989422804014327f;

    // ---- exact global sum S (deterministic, identical in every block) ----
    float local = 0.f;
#pragma unroll
    for (int s = 0; s < 32; ++s) {
        int idx = t + s * NTHR;
        if (idx < NTAPS) {
            int bb = idx / 2025;
            int r  = idx % 2025;
            int dz = r / 225;
            int r2 = r % 225;
            int dh = r2 / 15;
            int dw = r2 % 15;
            float bxy = bet_xy[bb], bzv = bet_z[bb], al = alpha[bb];
            float zd = (float)(dz - 4), hd = (float)(dh - 7), wd = (float)(dw - 7);
            float az = expf(-zd * zd / (2.f * bzv * bzv)) * (INV / bzv);
            float gh = expf(-hd * hd / (2.f * bxy * bxy)) * (INV / bxy);
            float gw = expf(-wd * wd / (2.f * bxy * bxy)) * (INV / bxy);
            local += 1.f - expf(-al * az * gh * gw);
        }
    }
    red[t] = local;
    __syncthreads();
    for (int s = 128; s > 0; s >>= 1) {
        if (t < s) red[t] += red[t + s];
        __syncthreads();
    }
    const float S = red[0];
    __syncthreads();

    // ---- own batch's coefficient table (65 values) into LDS ----
    if (t < NT * 13) {
        int n = t / 13;
        int k = t % 13;
        float bxy = bet_xy[b], bzv = bet_z[b], al = alpha[b];
        if (k < 8) {
            float d = (float)k;
            float g = expf(-d * d / (2.f * bxy * bxy)) * (INV / bxy);
            float p = g;
            for (int q = 0; q < n; ++q) p *= g;
            ct[n * 16 + k] = p;
        } else {
            float d = (float)(k - 8);
            float az = expf(-d * d / (2.f * bzv * bzv)) * (INV / bzv);
            float base = al * az;
            float p = base;
            for (int q = 0; q < n; ++q) p *= base;
            const float facs[NT] = {1.f, 2.f, 6.f, 24.f, 120.f};
            float sign = (n & 1) ? -1.f : 1.f;
            ct[n * 16 + k] = sign * p / (facs[n] * S);
        }
    }
    __syncthreads();

    // ---- hoist coefficients to wave-uniform scalars (SGPRs) ----
    float cg_[NT][8], cz_[NT][5];
#pragma unroll
    for (int n = 0; n < NT; ++n) {
#pragma unroll
        for (int k = 0; k < 8; ++k) cg_[n][k] = rfl(ct[n * 16 + k]);
#pragma unroll
        for (int k = 0; k < 5; ++k) cz_[n][k] = rfl(ct[n * 16 + 8 + k]);
    }
    __syncthreads();   // all ct/red reads done before xt staging overwrites alias

    // ---- staging descriptors (plane-invariant) ----
    const float* xb = x + (size_t)b * (D_ * HW_);
    int goff[NSEC], loff[NSEC];
#pragma unroll
    for (int k = 0; k < NSEC; ++k) {
        int i = t + k * NTHR;
        int r = i / XT_COLS, c = i - r * XT_COLS;
        int gh = h0 + r - 7, gw = w0 + c - 7;
        bool ok = (i < XT_CELLS) && gh >= 0 && gh < H_ && gw >= 0 && gw < W_;
        goff[k] = ok ? (gh * W_ + gw) : -1;
        loff[k] = (i < XT_CELLS) ? (r * XT_W + c) : (XT_SZ - 1);
    }
    // pre-stage first plane (zi = z0-4) into xt buffer 0
    {
        int zi0 = z0 - 4;
        if (zi0 >= 0) {
#pragma unroll
            for (int k = 0; k < NSEC; ++k) {
                float v = 0.f;
                if (goff[k] >= 0) v = xb[(size_t)zi0 * HW_ + goff[k]];
                xtb[loff[k]] = v;
            }
        }
    }

    // ---- per-thread roles (rotated per block so the two co-resident blocks
    //      put their heavy waves on different SIMDs) ----
    const int bid = blockIdx.x + (int)gridDim.x * (blockIdx.y + (int)gridDim.y * blockIdx.z);
    const int rt  = (t + ((bid >> 8) << 6)) & (NTHR - 1);

    // stage 1: 192 items = 12 rows x 16 col-groups (cols 0..63 of w-halo)
    const int s1r = rt >> 4, s1c = rt & 15;
    const int s1x = s1r * XT_W + 4 * s1c;          // xt read base (col-constant)
    const int s1w = s1r * R2_S + 4 * s1c;          // R' write base
    // stage 2: 144 items = 12 rows x 12 col-groups (output tile)
    const bool s2act = (rt < TH * 12);
    const int s2ro = rt / 12, s2cg = rt - 12 * s2ro;
    const int s2r  = s2ro * R2_S + 4 * s2cg;       // R' read base (window start)

    float4 acc[9];
#pragma unroll
    for (int k = 0; k < 9; ++k) acc[k] = make_float4(0.f, 0.f, 0.f, 0.f);

#pragma unroll 1
    for (int p = 0; p <= NP; ++p) {
        __syncthreads();   // xt[p&1] staged; R'[(p-1)&1] complete; R'[p&1] free

        const int zi = z0 - 4 + p;
        const bool do_s1 = (p < NP) && (zi >= 0) && (zi < D_) && (rt < 192);
        const int  zn    = zi + 1;
        const bool pvalid = (p + 1 < NP) && (zn >= 0) && (zn < D_);

        // prefetch next plane into registers (long-latency window = whole iter)
        float pv[NSEC];
        if (pvalid) {
            const float* xp = xb + (size_t)zn * HW_;
#pragma unroll
            for (int k = 0; k < NSEC; ++k) pv[k] = (goff[k] >= 0) ? xp[goff[k]] : 0.f;
        }

        // ---- stage 1: h-conv plane zi: xt[p&1] -> R'[p&1] ----
        if (do_s1) {
            const float* xt = xtb + (p & 1) * XT_SZ;
            float* Rw = Rb + (p & 1) * RBUF + s1w;
            // 15 column-constant reads, shared across all NT terms
            float4 ctr = *(const float4*)&xt[s1x + 7 * XT_W];
            float4 sp[7];
#pragma unroll
            for (int k = 1; k <= 7; ++k) {
                float4 a  = *(const float4*)&xt[s1x + (7 - k) * XT_W];
                float4 b2 = *(const float4*)&xt[s1x + (7 + k) * XT_W];
                sp[k - 1] = f4add(a, b2);
            }
#pragma unroll
            for (int n = 0; n < NT; ++n) {
                float c0 = cg_[n][0];
                float4 a;
                a.x = c0 * ctr.x; a.y = c0 * ctr.y;
                a.z = c0 * ctr.z; a.w = c0 * ctr.w;
#pragma unroll
                for (int k = 1; k <= 7; ++k) a = f4fma(cg_[n][k], sp[k - 1], a);
                *(float4*)&Rw[n * R2_PL] = a;
            }
        }

        // ---- stage 2: w-conv + z-scatter for plane ziq = zi-1 ----
        if (p >= 1 && s2act) {
            const int ziq = zi - 1;
            if (ziq >= 0 && ziq < D_) {
                const float* Rr = Rb + ((p - 1) & 1) * RBUF + s2r;
#pragma unroll
                for (int n = 0; n < NT; ++n) {
                    const float* R1 = Rr + n * R2_PL;
                    float win[20];
#pragma unroll
                    for (int q5 = 0; q5 < 5; ++q5) {
                        float4 a = *(const float4*)&R1[4 * q5];
                        win[4 * q5]     = a.x; win[4 * q5 + 1] = a.y;
                        win[4 * q5 + 2] = a.z; win[4 * q5 + 3] = a.w;
                    }
                    float c0 = cg_[n][0];
                    float4 qv;
                    qv.x = c0 * win[7];  qv.y = c0 * win[8];
                    qv.z = c0 * win[9];  qv.w = c0 * win[10];
#pragma unroll
                    for (int k = 1; k <= 7; ++k) {
                        float c = cg_[n][k];
                        qv.x = fmaf(c, win[7 - k]  + win[7 + k],  qv.x);
                        qv.y = fmaf(c, win[8 - k]  + win[8 + k],  qv.y);
                        qv.z = fmaf(c, win[9 - k]  + win[9 + k],  qv.z);
                        qv.w = fmaf(c, win[10 - k] + win[10 + k], qv.w);
                    }
                    acc[4] = f4fma(cz_[n][0], qv, acc[4]);
#pragma unroll
                    for (int j = 1; j <= 4; ++j) {
                        float cz = cz_[n][j];
                        acc[4 + j] = f4fma(cz, qv, acc[4 + j]);
                        acc[4 - j] = f4fma(cz, qv, acc[4 - j]);
                    }
                }
            }
            if (p - 1 >= 8) {
                int z = z0 + (p - 1 - 8);
                size_t o = ((size_t)(b * D_ + z) * H_ + (h0 + s2ro)) * W_ + (w0 + 4 * s2cg);
                *(float4*)&out[o] = acc[0];
            }
#pragma unroll
            for (int k = 0; k < 8; ++k) acc[k] = acc[k + 1];
            acc[8] = make_float4(0.f, 0.f, 0.f, 0.f);
        }

        // write prefetched plane into xt[(p+1)&1]
        if (pvalid) {
            float* xn = xtb + ((p + 1) & 1) * XT_SZ;
#pragma unroll
            for (int k = 0; k < NSEC; ++k) xn[loff[k]] = pv[k];
        }
    }
}

extern "C" void kernel_launch(void* const* d_in, const int* in_sizes, int n_in,
                              void* d_out, int out_size, void* d_ws, size_t ws_size,
                              hipStream_t stream) {
    const float* x      = (const float*)d_in[0];
    const float* bet_xy = (const float*)d_in[1];
    const float* bet_z  = (const float*)d_in[2];
    const float* alpha  = (const float*)d_in[3];
    float* out = (float*)d_out;

    hipLaunchKernelGGL(conv_kernel, dim3(W_ / TW, H_ / TH, B_ * (D_ / ZCHUNK)),
                       dim3(NTHR), 0, stream, x, bet_xy, bet_z, alpha, out);
}

// Round 2
// 159.791 us; speedup vs baseline: 1.0715x; 1.0715x over previous
//
#include <hip/hip_runtime.h>
#include <math.h>

#define B_ 4
#define D_ 32
#define H_ 192
#define W_ 192
#define HW_ (H_ * W_)

#define NT 5            // Taylor terms p = 1..5

#define TW 48           // 12 real col-groups; stage-2 runs 16 groups (4 garbage)
#define TH 12
#define NTHR 256
#define ZCHUNK 16
#define NP (ZCHUNK + 8) // 24 staged planes; NP+1 = 25 pipelined iterations

#define XT_H 26         // TH + 14
#define XT_COLS 62      // TW + 14 staged cols
#define XT_W 64         // row stride in words: addr = 4*lane + 64*dh (dense)
#define XT_CELLS (XT_H * XT_COLS)   // 1612
#define NSEC 7
#define XT_SZ (XT_H * XT_W)         // 1664

// Stage-1 output R': per term, 12 rows x 16 quads (64 words) -> addr = 4*lane
#define R2_PL (TH * XT_W)     // 768 words per term-plane
#define RBUF (NT * R2_PL)     // 3840

// +16 pad words: garbage-group window reads overrun last row by <=12 words
#define SMEM_WORDS (2 * XT_SZ + 2 * RBUF + 16)   // 3328 + 7680 + 16 = 11024 (44.1 KB)

#define NTAPS (B_ * 9 * 15 * 15)

__device__ inline float4 f4fma(float c, float4 a, float4 d) {
    d.x = fmaf(c, a.x, d.x); d.y = fmaf(c, a.y, d.y);
    d.z = fmaf(c, a.z, d.z); d.w = fmaf(c, a.w, d.w);
    return d;
}
__device__ inline float4 f4add(float4 a, float4 b) {
    a.x += b.x; a.y += b.y; a.z += b.z; a.w += b.w; return a;
}
__device__ inline float rfl(float x) {
    return __int_as_float(__builtin_amdgcn_readfirstlane(__float_as_int(x)));
}

// h-first separable-Taylor blur with ALL LDS accesses in the empirically
// conflict-free class: wave address = 4*lane + uniform offset.
//   stage 1 (rt<192): h-conv, reads xt[4*rt + 64*dh], writes R'[4*rt + 768n]
//   stage 2 (rt>=64): w-conv 16-wide, reads R'[4*l2 + 4i + 768n] (dense),
//                     groups 12-15 produce discarded values (overrun-safe)
__global__ __launch_bounds__(NTHR)
void conv_kernel(const float* __restrict__ x,
                 const float* __restrict__ bet_xy,
                 const float* __restrict__ bet_z,
                 const float* __restrict__ alpha,
                 float* __restrict__ out) {
    __shared__ __align__(16) float smem[SMEM_WORDS];
    float* xtb = smem;                 // [2][XT_SZ]
    float* Rb  = smem + 2 * XT_SZ;     // [2][NT][R2_PL] (+16 pad at end)
    float* red = smem;                 // alias: pre-loop only
    float* ct  = smem + 512;           // alias: pre-loop only, [NT][16]

    const int t  = threadIdx.x;
    const int w0 = blockIdx.x * TW;
    const int h0 = blockIdx.y * TH;
    const int bz = blockIdx.z;
    const int b  = bz & 3;
    const int z0 = (bz >> 2) * ZCHUNK;
    const float INV = 0.3989422804014327f;

    // ---- exact global sum S (deterministic, identical in every block) ----
    float local = 0.f;
#pragma unroll
    for (int s = 0; s < 32; ++s) {
        int idx = t + s * NTHR;
        if (idx < NTAPS) {
            int bb = idx / 2025;
            int r  = idx % 2025;
            int dz = r / 225;
            int r2 = r % 225;
            int dh = r2 / 15;
            int dw = r2 % 15;
            float bxy = bet_xy[bb], bzv = bet_z[bb], al = alpha[bb];
            float zd = (float)(dz - 4), hd = (float)(dh - 7), wd = (float)(dw - 7);
            float az = expf(-zd * zd / (2.f * bzv * bzv)) * (INV / bzv);
            float gh = expf(-hd * hd / (2.f * bxy * bxy)) * (INV / bxy);
            float gw = expf(-wd * wd / (2.f * bxy * bxy)) * (INV / bxy);
            local += 1.f - expf(-al * az * gh * gw);
        }
    }
    red[t] = local;
    __syncthreads();
    for (int s = 128; s > 0; s >>= 1) {
        if (t < s) red[t] += red[t + s];
        __syncthreads();
    }
    const float S = red[0];
    __syncthreads();

    // ---- own batch's coefficient table (65 values) into LDS ----
    if (t < NT * 13) {
        int n = t / 13;
        int k = t % 13;
        float bxy = bet_xy[b], bzv = bet_z[b], al = alpha[b];
        if (k < 8) {
            float d = (float)k;
            float g = expf(-d * d / (2.f * bxy * bxy)) * (INV / bxy);
            float p = g;
            for (int q = 0; q < n; ++q) p *= g;
            ct[n * 16 + k] = p;
        } else {
            float d = (float)(k - 8);
            float az = expf(-d * d / (2.f * bzv * bzv)) * (INV / bzv);
            float base = al * az;
            float p = base;
            for (int q = 0; q < n; ++q) p *= base;
            const float facs[NT] = {1.f, 2.f, 6.f, 24.f, 120.f};
            float sign = (n & 1) ? -1.f : 1.f;
            ct[n * 16 + k] = sign * p / (facs[n] * S);
        }
    }
    __syncthreads();

    // ---- hoist coefficients to wave-uniform scalars (SGPRs) ----
    float cg_[NT][8], cz_[NT][5];
#pragma unroll
    for (int n = 0; n < NT; ++n) {
#pragma unroll
        for (int k = 0; k < 8; ++k) cg_[n][k] = rfl(ct[n * 16 + k]);
#pragma unroll
        for (int k = 0; k < 5; ++k) cz_[n][k] = rfl(ct[n * 16 + 8 + k]);
    }
    __syncthreads();   // all ct/red reads done before xt staging overwrites alias

    // ---- staging descriptors (plane-invariant) ----
    const float* xb = x + (size_t)b * (D_ * HW_);
    int goff[NSEC], loff[NSEC];
#pragma unroll
    for (int k = 0; k < NSEC; ++k) {
        int i = t + k * NTHR;
        int r = i / XT_COLS, c = i - r * XT_COLS;
        int gh = h0 + r - 7, gw = w0 + c - 7;
        bool ok = (i < XT_CELLS) && gh >= 0 && gh < H_ && gw >= 0 && gw < W_;
        goff[k] = ok ? (gh * W_ + gw) : -1;
        loff[k] = (i < XT_CELLS) ? (r * XT_W + c) : (XT_SZ - 1);
    }
    // zero the 2 pad cols (62,63) of both xt buffers (read as dead win slots)
    if (t < XT_H * 2) {
        int r = t >> 1, c = 62 + (t & 1);
        xtb[r * XT_W + c] = 0.f;
        xtb[XT_SZ + r * XT_W + c] = 0.f;
    }
    // pre-stage first plane (zi = z0-4) into xt buffer 0
    {
        int zi0 = z0 - 4;
        if (zi0 >= 0) {
#pragma unroll
            for (int k = 0; k < NSEC; ++k) {
                float v = 0.f;
                if (goff[k] >= 0) v = xb[(size_t)zi0 * HW_ + goff[k]];
                xtb[loff[k]] = v;
            }
        }
    }

    // ---- per-thread roles; rotate by 128 per adjacent block so co-resident
    //      blocks' heavy waves land on different SIMDs ----
    const int bid = blockIdx.x + (int)gridDim.x * (blockIdx.y + (int)gridDim.y * blockIdx.z);
    const int rt  = (t + ((bid & 1) << 7)) & (NTHR - 1);

    // stage 1: 192 items = 12 rows x 16 quads; addr base = 4*rt
    const bool s1act = (rt < 192);
    // stage 2: 192 items on rt in [64,256): l2 = rt-64; 12 rows x 16 groups
    const bool s2on = (rt >= 64);
    const int l2 = rt - 64;
    const int s2ro = l2 >> 4, s2cg = l2 & 15;
    const bool s2store = s2on && (s2cg < 12);

    float4 acc[9];
#pragma unroll
    for (int k = 0; k < 9; ++k) acc[k] = make_float4(0.f, 0.f, 0.f, 0.f);

#pragma unroll 1
    for (int p = 0; p <= NP; ++p) {
        __syncthreads();   // xt[p&1] staged; R'[(p-1)&1] complete; R'[p&1] free

        const int zi = z0 - 4 + p;
        const bool do_s1 = (p < NP) && (zi >= 0) && (zi < D_) && s1act;
        const int  zn    = zi + 1;
        const bool pvalid = (p + 1 < NP) && (zn >= 0) && (zn < D_);

        // prefetch next plane into registers (long-latency window = whole iter)
        float pv[NSEC];
        if (pvalid) {
            const float* xp = xb + (size_t)zn * HW_;
#pragma unroll
            for (int k = 0; k < NSEC; ++k) pv[k] = (goff[k] >= 0) ? xp[goff[k]] : 0.f;
        }

        // ---- stage 1: h-conv plane zi: xt[p&1] -> R'[p&1] (all dense) ----
        if (do_s1) {
            const float4* x4 = (const float4*)(xtb + (p & 1) * XT_SZ + 4 * rt);
            float4* R4 = (float4*)(Rb + (p & 1) * RBUF) + rt;
            float4 ctr = x4[7 * 16];
            float4 sp[7];
#pragma unroll
            for (int k = 1; k <= 7; ++k)
                sp[k - 1] = f4add(x4[(7 - k) * 16], x4[(7 + k) * 16]);
#pragma unroll
            for (int n = 0; n < NT; ++n) {
                float c0 = cg_[n][0];
                float4 a;
                a.x = c0 * ctr.x; a.y = c0 * ctr.y;
                a.z = c0 * ctr.z; a.w = c0 * ctr.w;
#pragma unroll
                for (int k = 1; k <= 7; ++k) a = f4fma(cg_[n][k], sp[k - 1], a);
                R4[n * (R2_PL / 4)] = a;
            }
        }

        // ---- stage 2: w-conv + z-scatter for plane ziq = zi-1 (dense) ----
        if (p >= 1 && s2on) {
            const int ziq = zi - 1;
            if (ziq >= 0 && ziq < D_) {
                const float4* R4 = (const float4*)(Rb + ((p - 1) & 1) * RBUF) + l2;
#pragma unroll
                for (int n = 0; n < NT; ++n) {
                    float win[20];
#pragma unroll
                    for (int i = 0; i < 5; ++i) {
                        float4 a = R4[n * (R2_PL / 4) + i];
                        win[4 * i]     = a.x; win[4 * i + 1] = a.y;
                        win[4 * i + 2] = a.z; win[4 * i + 3] = a.w;
                    }
                    float c0 = cg_[n][0];
                    float4 qv;
                    qv.x = c0 * win[7];  qv.y = c0 * win[8];
                    qv.z = c0 * win[9];  qv.w = c0 * win[10];
#pragma unroll
                    for (int k = 1; k <= 7; ++k) {
                        float c = cg_[n][k];
                        qv.x = fmaf(c, win[7 - k]  + win[7 + k],  qv.x);
                        qv.y = fmaf(c, win[8 - k]  + win[8 + k],  qv.y);
                        qv.z = fmaf(c, win[9 - k]  + win[9 + k],  qv.z);
                        qv.w = fmaf(c, win[10 - k] + win[10 + k], qv.w);
                    }
                    acc[4] = f4fma(cz_[n][0], qv, acc[4]);
#pragma unroll
                    for (int j = 1; j <= 4; ++j) {
                        float cz = cz_[n][j];
                        acc[4 + j] = f4fma(cz, qv, acc[4 + j]);
                        acc[4 - j] = f4fma(cz, qv, acc[4 - j]);
                    }
                }
            }
            if (p - 1 >= 8 && s2store) {
                int z = z0 + (p - 1 - 8);
                size_t o = ((size_t)(b * D_ + z) * H_ + (h0 + s2ro)) * W_ + (w0 + 4 * s2cg);
                *(float4*)&out[o] = acc[0];
            }
#pragma unroll
            for (int k = 0; k < 8; ++k) acc[k] = acc[k + 1];
            acc[8] = make_float4(0.f, 0.f, 0.f, 0.f);
        }

        // write prefetched plane into xt[(p+1)&1]
        if (pvalid) {
            float* xn = xtb + ((p + 1) & 1) * XT_SZ;
#pragma unroll
            for (int k = 0; k < NSEC; ++k) xn[loff[k]] = pv[k];
        }
    }
}

extern "C" void kernel_launch(void* const* d_in, const int* in_sizes, int n_in,
                              void* d_out, int out_size, void* d_ws, size_t ws_size,
                              hipStream_t stream) {
    const float* x      = (const float*)d_in[0];
    const float* bet_xy = (const float*)d_in[1];
    const float* bet_z  = (const float*)d_in[2];
    const float* alpha  = (const float*)d_in[3];
    float* out = (float*)d_out;

    hipLaunchKernelGGL(conv_kernel, dim3(W_ / TW, H_ / TH, B_ * (D_ / ZCHUNK)),
                       dim3(NTHR), 0, stream, x, bet_xy, bet_z, alpha, out);
}